// Round 3
// baseline (168.138 us; speedup 1.0000x reference)
//
#include <hip/hip_runtime.h>
#include <math.h>

#define B_    32
#define CIN_  256
#define HW_   784
#define H_    28
#define W_    28
#define COUT_ 256
#define KEXP_ 4
#define HID_  64

typedef short short8 __attribute__((ext_vector_type(8)));
typedef unsigned short ushort4v __attribute__((ext_vector_type(4)));
typedef unsigned short ushort8v __attribute__((ext_vector_type(8)));
typedef float floatx16 __attribute__((ext_vector_type(16)));
typedef float float8v __attribute__((ext_vector_type(8)));

__device__ __forceinline__ unsigned short f2bf(float f) {
    union { float f; unsigned int u; } v; v.f = f;
    unsigned int r = (v.u + 0x7FFFu + ((v.u >> 16) & 1u)) >> 16;
    return (unsigned short)r;
}

// ---------------- Kernel 1: transpose + partial pool (no atomics) ----------------
// x [b][ic][px] f32 -> x_t [b][px][ic] bf16 ; partial[(b*25+pxt)*256 + ic] = rowsum/784
__global__ __launch_bounds__(256) void xpose_pool_kernel(const float* __restrict__ x,
                                                         unsigned short* __restrict__ x_t,
                                                         float* __restrict__ partial) {
    __shared__ float tile[32][33];
    int bid = blockIdx.x;              // 32 * 8 * 25
    int b   = bid / 200;
    int rem = bid - b * 200;
    int icg = rem / 25;
    int pxt = rem % 25;
    int ic0 = icg * 32;
    int px0 = pxt * 32;
    int t = threadIdx.x;
    int c = t & 31, rr = t >> 5;
    #pragma unroll
    for (int r = 0; r < 4; ++r) {
        int icr = rr + r * 8;
        int px = px0 + c;
        float v = (px < HW_) ? x[((size_t)(b * CIN_ + ic0 + icr)) * HW_ + px] : 0.f;
        tile[icr][c] = v;
    }
    __syncthreads();
    #pragma unroll
    for (int r = 0; r < 4; ++r) {
        int pxr = rr + r * 8;
        int px = px0 + pxr;
        if (px < HW_)
            x_t[((size_t)b * HW_ + px) * CIN_ + ic0 + c] = f2bf(tile[c][pxr]);
    }
    if (t < 32) {
        float s = 0.f;
        #pragma unroll
        for (int cc = 0; cc < 32; ++cc) s += tile[t][cc];
        partial[((size_t)b * 25 + pxt) * CIN_ + ic0 + t] = s * (1.0f / HW_);
    }
}

// ---------------- standalone pool (fallback path only) ----------------
__global__ __launch_bounds__(256) void pool_kernel(const float* __restrict__ x,
                                                   float* __restrict__ pooled) {
    int w = blockIdx.x * 4 + (threadIdx.x >> 6);
    int lane = threadIdx.x & 63;
    const float* p = x + (size_t)w * HW_;
    float s = 0.f;
    for (int i = lane; i < HW_; i += 64) s += p[i];
    for (int off = 32; off; off >>= 1) s += __shfl_down(s, off);
    if (lane == 0) pooled[w] = s * (1.0f / HW_);
}

// ---------------- Kernel 2: SE MLP + softmax (reads partial pools) ----------------
__global__ __launch_bounds__(256) void se3_kernel(const float* __restrict__ partial,
                                                  const float* __restrict__ fc1_w,
                                                  const float* __restrict__ fc2_w,
                                                  const float* __restrict__ fc2_b,
                                                  float* __restrict__ prob) {
    __shared__ float pl[CIN_];
    __shared__ float h[HID_];
    __shared__ float wb[16640];
    int b = blockIdx.x, t = threadIdx.x;
    {
        float s = 0.f;
        for (int pt = 0; pt < 25; ++pt)
            s += partial[((size_t)b * 25 + pt) * CIN_ + t];
        pl[t] = s;
    }
    #pragma unroll
    for (int i = 0; i < 16; ++i) {
        int l = t + i * 256;
        float4 v = *(const float4*)(fc1_w + (size_t)l * 4);
        int r = l >> 6, cc = (l & 63) * 4;
        float* dst = &wb[r * 257 + cc];
        dst[0] = v.x; dst[1] = v.y; dst[2] = v.z; dst[3] = v.w;
    }
    __syncthreads();
    if (t < HID_) {
        float s = 0.f;
        const float* wr = &wb[t * 257];
        for (int c = 0; c < CIN_; ++c) s += pl[c] * wr[c];
        h[t] = fmaxf(s, 0.f);
    }
    float yk[KEXP_];
    for (int k = 0; k < KEXP_; ++k) {
        __syncthreads();
        #pragma unroll
        for (int i = 0; i < 16; ++i) {
            int l = t + i * 256;
            float4 v = *(const float4*)(fc2_w + (size_t)k * COUT_ * HID_ + (size_t)l * 4);
            int o = l >> 4, jj = (l & 15) * 4;
            float* dst = &wb[o * 65 + jj];
            dst[0] = v.x; dst[1] = v.y; dst[2] = v.z; dst[3] = v.w;
        }
        __syncthreads();
        float s = fc2_b[k * COUT_ + t];
        const float* wr = &wb[t * 65];
        #pragma unroll
        for (int j = 0; j < HID_; ++j) s += h[j] * wr[j];
        yk[k] = s * 0.125f;
    }
    float m = yk[0];
    for (int k = 1; k < KEXP_; ++k) m = fmaxf(m, yk[k]);
    float e[KEXP_], sum = 0.f;
    for (int k = 0; k < KEXP_; ++k) { e[k] = expf(yk[k] - m); sum += e[k]; }
    float inv = 1.0f / sum;
    for (int k = 0; k < KEXP_; ++k)
        prob[b * (KEXP_ * COUT_) + k * COUT_ + t] = e[k] * inv;
}

// ---------------- SE from pooled (fallback path only) ----------------
__global__ __launch_bounds__(256) void se2_kernel(const float* __restrict__ pooled,
                                                  const float* __restrict__ fc1_w,
                                                  const float* __restrict__ fc2_w,
                                                  const float* __restrict__ fc2_b,
                                                  float* __restrict__ prob) {
    __shared__ float pl[CIN_];
    __shared__ float h[HID_];
    __shared__ float wb[16640];
    int b = blockIdx.x, t = threadIdx.x;
    pl[t] = pooled[b * CIN_ + t];
    #pragma unroll
    for (int i = 0; i < 16; ++i) {
        int l = t + i * 256;
        float4 v = *(const float4*)(fc1_w + (size_t)l * 4);
        int r = l >> 6, cc = (l & 63) * 4;
        float* dst = &wb[r * 257 + cc];
        dst[0] = v.x; dst[1] = v.y; dst[2] = v.z; dst[3] = v.w;
    }
    __syncthreads();
    if (t < HID_) {
        float s = 0.f;
        const float* wr = &wb[t * 257];
        for (int c = 0; c < CIN_; ++c) s += pl[c] * wr[c];
        h[t] = fmaxf(s, 0.f);
    }
    float yk[KEXP_];
    for (int k = 0; k < KEXP_; ++k) {
        __syncthreads();
        #pragma unroll
        for (int i = 0; i < 16; ++i) {
            int l = t + i * 256;
            float4 v = *(const float4*)(fc2_w + (size_t)k * COUT_ * HID_ + (size_t)l * 4);
            int o = l >> 4, jj = (l & 15) * 4;
            float* dst = &wb[o * 65 + jj];
            dst[0] = v.x; dst[1] = v.y; dst[2] = v.z; dst[3] = v.w;
        }
        __syncthreads();
        float s = fc2_b[k * COUT_ + t];
        const float* wr = &wb[t * 65];
        #pragma unroll
        for (int j = 0; j < HID_; ++j) s += h[j] * wr[j];
        yk[k] = s * 0.125f;
    }
    float m = yk[0];
    for (int k = 1; k < KEXP_; ++k) m = fmaxf(m, yk[k]);
    float e[KEXP_], sum = 0.f;
    for (int k = 0; k < KEXP_; ++k) { e[k] = expf(yk[k] - m); sum += e[k]; }
    float inv = 1.0f / sum;
    for (int k = 0; k < KEXP_; ++k)
        prob[b * (KEXP_ * COUT_) + k * COUT_ + t] = e[k] * inv;
}

// ---------------- Kernel 3: weight -> f32 MFMA-fragment layout (batch-independent) ----------------
// wf element (k, oc, ic, rs) at:
//   (((k*4 + icc)*4 + kk)*9 + rs)*4096 + og*512 + (kh*32+ml)*8 + j      [f32 elems]
// where icc=ic>>6, kk=(ic>>4)&3, kh=(ic>>3)&1, j=ic&7, og=oc>>5, ml=oc&31.
// grid = 128: og = gid&7, icc = (gid>>3)&3, kk = gid>>5
__global__ __launch_bounds__(256) void wfrag_kernel(const float* __restrict__ weight,
                                                    float* __restrict__ wf) {
    __shared__ float wlds[4][32][145];   // [k][oc-ml][(kh*8+j)*9+rs], pad 144->145 (odd stride)
    int gid = blockIdx.x;
    int og  = gid & 7;
    int icc = (gid >> 3) & 3;
    int kk  = gid >> 5;
    int oc0 = og * 32;
    int ic0 = icc * 64 + kk * 16;
    int t = threadIdx.x;

    // stage weight[k][oc0..+31][ic0..+15][rs 0..8] -> LDS (each element read once globally)
    #pragma unroll
    for (int i = 0; i < 18; ++i) {
        int idx = t + i * 256;             // 0..4607 float4s
        int k  = idx / 1152;
        int r  = idx - k * 1152;
        int oc = r / 36;
        int f4 = r - oc * 36;
        float4 v = *(const float4*)(weight + ((size_t)(k * COUT_ + oc0 + oc) * CIN_ + ic0) * 9 + f4 * 4);
        float* dst = &wlds[k][oc][f4 * 4];
        dst[0] = v.x; dst[1] = v.y; dst[2] = v.z; dst[3] = v.w;
    }
    __syncthreads();

    int lane = t & 63, wv = t >> 6;       // wave wv handles expert k = wv
    int ml = lane & 31, kh = lane >> 5;

    for (int rs = 0; rs < 9; ++rs) {
        float8v v;
        #pragma unroll
        for (int j = 0; j < 8; ++j)
            v[j] = wlds[wv][ml][(kh * 8 + j) * 9 + rs];
        *(float8v*)(wf + ((size_t)(((wv * 4 + icc) * 4 + kk) * 9 + rs)) * 4096
                       + og * 512 + lane * 8) = v;
    }
}

// ---------------- Kernel 4: MFMA implicit-GEMM conv, fused expert aggregation ----------------
// grid = 256: b = gid&31, half = (gid>>5)&1, rowblk = gid>>6 (7 rows each)
__global__ __launch_bounds__(256, 1) void conv_mfma4_kernel(const unsigned short* __restrict__ x_t,
                                                            const float* __restrict__ wf,
                                                            const float* __restrict__ prob,
                                                            float* __restrict__ out) {
    __shared__ __align__(16) short Xs[2][9 * 35 * 72];   // 2 x 45360 B = 90720 B

    int gid = blockIdx.x;
    int b      = gid & 31;
    int half   = (gid >> 5) & 1;
    int oc0    = half * 128;
    int rowblk = gid >> 6;
    int py0 = rowblk * 7;

    int t = threadIdx.x;
    int lane = t & 63, w = t >> 6;
    int ml = lane & 31, kh = lane >> 5;
    int og = half * 4 + w;

    floatx16 acc[7];
    #pragma unroll
    for (int j = 0; j < 7; ++j)
        #pragma unroll
        for (int r = 0; r < 16; ++r) acc[j][r] = 0.f;

    const unsigned short* xtb = x_t + (size_t)b * HW_ * CIN_;
    // fragment base: wf + og*512 + lane*8 ; strides (f32 elems):
    //   k: 589824, icc: 147456, kk: 36864, rs: 4096 (tap ky stride = 12288)
    const float* wfl = wf + og * 512 + lane * 8;

    // per-lane expert probabilities for this lane's oc row (oc = oc0 + w*32 + ml)
    float p0 = prob[(size_t)b * (KEXP_ * COUT_) + 0 * COUT_ + oc0 + w * 32 + ml];
    float p1 = prob[(size_t)b * (KEXP_ * COUT_) + 1 * COUT_ + oc0 + w * 32 + ml];
    float p2 = prob[(size_t)b * (KEXP_ * COUT_) + 2 * COUT_ + oc0 + w * 32 + ml];
    float p3 = prob[(size_t)b * (KEXP_ * COUT_) + 3 * COUT_ + oc0 + w * 32 + ml];

    // ---- stage chunk 0 into buf 0 ----
    {
        #pragma unroll
        for (int i = 0; i < 10; ++i) {
            int l = t + i * 256;
            if (l < 2520) {
                int pos = l >> 3, g = l & 7;
                int row = pos / 35, col = pos - row * 35;
                int gy = py0 - 1 + row, gx = col - 1;
                short8 v = (short8)0;
                if ((unsigned)gy < 28u && (unsigned)gx < 28u)
                    v = *(const short8*)(xtb + ((size_t)(gy * W_ + gx)) * CIN_ + g * 8);
                *(short8*)&Xs[0][pos * 72 + g * 8] = v;
            }
        }
    }

    // ---- prologue: issue raw expert-fragment loads for step (icc=0, kk=0, dx=0) ----
    float8v Rw[3][4];                     // [tap][k], 96 VGPRs (fine at 1 wave/SIMD)
    #pragma unroll
    for (int tap = 0; tap < 3; ++tap)
        #pragma unroll
        for (int k = 0; k < 4; ++k)
            Rw[tap][k] = *(const float8v*)(wfl + (size_t)k * 589824 + (size_t)tap * 12288);
    // rolling "next to issue" state
    int dxn = 1, kkn = 0, icn = 0;

    __syncthreads();

    for (int c = 0; c < 4; ++c) {
        int ic0 = c * 64;
        const short* xb = &Xs[c & 1][0];

        // issue staging loads for next chunk (held in regs, written after compute)
        short8 Xl[10];
        if (c < 3) {
            #pragma unroll
            for (int i = 0; i < 10; ++i) {
                int l = t + i * 256;
                short8 v = (short8)0;
                if (l < 2520) {
                    int pos = l >> 3, g = l & 7;
                    int row = pos / 35, col = pos - row * 35;
                    int gy = py0 - 1 + row, gx = col - 1;
                    if ((unsigned)gy < 28u && (unsigned)gx < 28u)
                        v = *(const short8*)(xtb + ((size_t)(gy * W_ + gx)) * CIN_ + ic0 + 64 + g * 8);
                }
                Xl[i] = v;
            }
        }

        for (int kk = 0; kk < 4; ++kk) {
            for (int dx = 0; dx < 3; ++dx) {
                // combine current step's A fragments from raw expert fragments (f32, exact)
                short8 A0, A1, A2;
                {
                    #pragma unroll
                    for (int tap = 0; tap < 3; ++tap) {
                        short8 Ax;
                        #pragma unroll
                        for (int j = 0; j < 8; ++j) {
                            float s = p0 * Rw[tap][0][j] + p1 * Rw[tap][1][j]
                                    + p2 * Rw[tap][2][j] + p3 * Rw[tap][3][j];
                            Ax[j] = (short)f2bf(s);
                        }
                        if (tap == 0) A0 = Ax; else if (tap == 1) A1 = Ax; else A2 = Ax;
                    }
                }
                // issue raw loads for next step (Rw regs free after combine)
                if (icn < 256) {
                    const float* ap = wfl + (size_t)(icn >> 6) * 147456
                                          + (size_t)kkn * 36864 + (size_t)dxn * 4096;
                    #pragma unroll
                    for (int tap = 0; tap < 3; ++tap)
                        #pragma unroll
                        for (int k = 0; k < 4; ++k)
                            Rw[tap][k] = *(const float8v*)(ap + (size_t)k * 589824
                                                              + (size_t)tap * 12288);
                    ++dxn;
                    if (dxn == 3) { dxn = 0; ++kkn; if (kkn == 4) { kkn = 0; icn += 64; } }
                }
                // compute: 9 Xs rows, B reused across 3 dy taps
                int va = (ml + dx) * 72 + kk * 16 + kh * 8;
                #pragma unroll
                for (int r = 0; r < 9; ++r) {
                    short8 Bf = *(const short8*)&xb[r * 2520 + va];
                    if (r <= 6)
                        acc[r]     = __builtin_amdgcn_mfma_f32_32x32x16_bf16(A0, Bf, acc[r], 0, 0, 0);
                    if (r >= 1 && r - 1 <= 6)
                        acc[r - 1] = __builtin_amdgcn_mfma_f32_32x32x16_bf16(A1, Bf, acc[r - 1], 0, 0, 0);
                    if (r >= 2)
                        acc[r - 2] = __builtin_amdgcn_mfma_f32_32x32x16_bf16(A2, Bf, acc[r - 2], 0, 0, 0);
                }
            }
        }

        if (c < 3) {
            short* dstb = &Xs[(c & 1) ^ 1][0];
            #pragma unroll
            for (int i = 0; i < 10; ++i) {
                int l = t + i * 256;
                if (l < 2520) {
                    int pos = l >> 3, g = l & 7;
                    *(short8*)&dstb[pos * 72 + g * 8] = Xl[i];
                }
            }
        }
        __syncthreads();
    }

    // ---- epilogue: D layout col=lane&31, row=(reg&3)+8*(reg>>2)+4*(lane>>5) ----
    if (ml < W_) {
        #pragma unroll
        for (int j = 0; j < 7; ++j) {
            float* op = out + ((size_t)(b * COUT_ + oc0 + w * 32)) * HW_ + (py0 + j) * W_ + ml;
            #pragma unroll
            for (int r = 0; r < 16; ++r) {
                int ocd = (r & 3) + 8 * (r >> 2) + 4 * kh;
                op[(size_t)ocd * HW_] = acc[j][r];
            }
        }
    }
}

// ---------------- Fallback fp32 direct conv ----------------
__global__ __launch_bounds__(256) void conv_kernel(const float* __restrict__ x,
                                                   const float* __restrict__ weight,
                                                   const float* __restrict__ prob,
                                                   float* __restrict__ out) {
    __shared__ float xs[30 * 30];
    __shared__ float wagg[8][32][12];
    __shared__ float pl[KEXP_][8];

    int b  = blockIdx.x >> 5;
    int o0 = (blockIdx.x & 31) * 8;
    int t  = threadIdx.x;

    if (t < 32) {
        int k = t >> 3, oc = t & 7;
        pl[k][oc] = prob[b * (KEXP_ * COUT_) + k * COUT_ + o0 + oc];
    }
    int p0 = t;
    int pr[4], pc[4];
    bool pv[4];
    #pragma unroll
    for (int j = 0; j < 4; ++j) {
        int p = p0 + j * 256;
        pv[j] = p < HW_;
        pr[j] = p / W_;
        pc[j] = p % W_;
    }
    float acc[8][4];
    #pragma unroll
    for (int oc = 0; oc < 8; ++oc)
        #pragma unroll
        for (int j = 0; j < 4; ++j) acc[oc][j] = 0.f;

    int aoc = t >> 5, aii = t & 31;

    for (int ic0 = 0; ic0 < CIN_; ic0 += 32) {
        __syncthreads();
        {
            float w9[9];
            #pragma unroll
            for (int j = 0; j < 9; ++j) w9[j] = 0.f;
            int i = ic0 + aii;
            #pragma unroll
            for (int k = 0; k < KEXP_; ++k) {
                float pk = pl[k][aoc];
                const float* wp = weight + ((size_t)(k * COUT_ + o0 + aoc) * CIN_ + i) * 9;
                #pragma unroll
                for (int j = 0; j < 9; ++j) w9[j] += pk * wp[j];
            }
            #pragma unroll
            for (int j = 0; j < 9; ++j) wagg[aoc][aii][j] = w9[j];
        }
        for (int ii = 0; ii < 32; ++ii) {
            int i = ic0 + ii;
            __syncthreads();
            const float* xp = x + (size_t)(b * CIN_ + i) * HW_;
            for (int e = t; e < 900; e += 256) {
                int ry = e / 30, cx = e - ry * 30;
                int gy = ry - 1, gx = cx - 1;
                float v = 0.f;
                if ((unsigned)gy < 28u && (unsigned)gx < 28u) v = xp[gy * W_ + gx];
                xs[e] = v;
            }
            __syncthreads();
            float xv[4][9];
            #pragma unroll
            for (int j = 0; j < 4; ++j) {
                if (pv[j]) {
                    const float* xr = &xs[pr[j] * 30 + pc[j]];
                    xv[j][0] = xr[0];  xv[j][1] = xr[1];  xv[j][2] = xr[2];
                    xv[j][3] = xr[30]; xv[j][4] = xr[31]; xv[j][5] = xr[32];
                    xv[j][6] = xr[60]; xv[j][7] = xr[61]; xv[j][8] = xr[62];
                } else {
                    #pragma unroll
                    for (int q = 0; q < 9; ++q) xv[j][q] = 0.f;
                }
            }
            #pragma unroll
            for (int oc = 0; oc < 8; ++oc) {
                float4 wa = *(const float4*)&wagg[oc][ii][0];
                float4 wb2 = *(const float4*)&wagg[oc][ii][4];
                float  wc = wagg[oc][ii][8];
                #pragma unroll
                for (int j = 0; j < 4; ++j) {
                    acc[oc][j] += xv[j][0] * wa.x + xv[j][1] * wa.y + xv[j][2] * wa.z
                                + xv[j][3] * wa.w + xv[j][4] * wb2.x + xv[j][5] * wb2.y
                                + xv[j][6] * wb2.z + xv[j][7] * wb2.w + xv[j][8] * wc;
                }
            }
        }
    }
    #pragma unroll
    for (int oc = 0; oc < 8; ++oc) {
        float* op = out + (size_t)(b * COUT_ + o0 + oc) * HW_ + p0;
        #pragma unroll
        for (int j = 0; j < 4; ++j)
            if (pv[j]) op[j * 256] = acc[oc][j];
    }
}

extern "C" void kernel_launch(void* const* d_in, const int* in_sizes, int n_in,
                              void* d_out, int out_size, void* d_ws, size_t ws_size,
                              hipStream_t stream) {
    const float* x     = (const float*)d_in[0];
    const float* fc1_w = (const float*)d_in[1];
    const float* fc2_w = (const float*)d_in[2];
    const float* fc2_b = (const float*)d_in[3];
    const float* weight= (const float*)d_in[4];
    float* out = (float*)d_out;

    char* ws = (char*)d_ws;
    // layout (main path), no overlaps:
    //   prob    @0         (4 KB used, 128 KB reserved)
    //   x_t     @131072    (12.845 MB bf16)
    //   partial @12976128  (819 KB f32)
    //   wf      @13795328  (9.437 MB f32 fragment-layout weights)
    float* prob = (float*)(ws);
    unsigned short* x_t = (unsigned short*)(ws + 131072);
    float* partial = (float*)(ws + 12976128);
    float* wf = (float*)(ws + 13795328);
    const size_t WS_NEED = 13795328 + (size_t)KEXP_ * COUT_ * CIN_ * 9 * 4;  // 23232512

    if (ws_size >= WS_NEED) {
        xpose_pool_kernel<<<B_ * 8 * 25, 256, 0, stream>>>(x, x_t, partial);
        se3_kernel<<<B_, 256, 0, stream>>>(partial, fc1_w, fc2_w, fc2_b, prob);
        wfrag_kernel<<<128, 256, 0, stream>>>(weight, wf);
        conv_mfma4_kernel<<<256, 256, 0, stream>>>(x_t, wf, prob, out);
    } else {
        float* pooled = (float*)(ws + 131072);
        pool_kernel<<<(B_ * CIN_) / 4, 256, 0, stream>>>(x, pooled);
        se2_kernel<<<B_, 256, 0, stream>>>(pooled, fc1_w, fc2_w, fc2_b, prob);
        conv_kernel<<<B_ * (COUT_ / 8), 256, 0, stream>>>(x, weight, prob, out);
    }
}

// Round 4
// 146.778 us; speedup vs baseline: 1.1455x; 1.1455x over previous
//
#include <hip/hip_runtime.h>
#include <math.h>

#define B_    32
#define CIN_  256
#define HW_   784
#define H_    28
#define W_    28
#define COUT_ 256
#define KEXP_ 4
#define HID_  64

typedef short short8 __attribute__((ext_vector_type(8)));
typedef unsigned short ushort4v __attribute__((ext_vector_type(4)));
typedef unsigned short ushort8v __attribute__((ext_vector_type(8)));
typedef float floatx16 __attribute__((ext_vector_type(16)));
typedef float float8v __attribute__((ext_vector_type(8)));

__device__ __forceinline__ unsigned short f2bf(float f) {
    union { float f; unsigned int u; } v; v.f = f;
    unsigned int r = (v.u + 0x7FFFu + ((v.u >> 16) & 1u)) >> 16;
    return (unsigned short)r;
}

// ---------------- Kernel 1: transpose + partial pool (no atomics) ----------------
// x [b][ic][px] f32 -> x_t [b][px][ic] bf16 ; partial[(b*25+pxt)*256 + ic] = rowsum/784
__global__ __launch_bounds__(256) void xpose_pool_kernel(const float* __restrict__ x,
                                                         unsigned short* __restrict__ x_t,
                                                         float* __restrict__ partial) {
    __shared__ float tile[32][33];
    int bid = blockIdx.x;              // 32 * 8 * 25
    int b   = bid / 200;
    int rem = bid - b * 200;
    int icg = rem / 25;
    int pxt = rem % 25;
    int ic0 = icg * 32;
    int px0 = pxt * 32;
    int t = threadIdx.x;
    int c = t & 31, rr = t >> 5;
    #pragma unroll
    for (int r = 0; r < 4; ++r) {
        int icr = rr + r * 8;
        int px = px0 + c;
        float v = (px < HW_) ? x[((size_t)(b * CIN_ + ic0 + icr)) * HW_ + px] : 0.f;
        tile[icr][c] = v;
    }
    __syncthreads();
    #pragma unroll
    for (int r = 0; r < 4; ++r) {
        int pxr = rr + r * 8;
        int px = px0 + pxr;
        if (px < HW_)
            x_t[((size_t)b * HW_ + px) * CIN_ + ic0 + c] = f2bf(tile[c][pxr]);
    }
    if (t < 32) {
        float s = 0.f;
        #pragma unroll
        for (int cc = 0; cc < 32; ++cc) s += tile[t][cc];
        partial[((size_t)b * 25 + pxt) * CIN_ + ic0 + t] = s * (1.0f / HW_);
    }
}

// ---------------- standalone pool (fallback path only) ----------------
__global__ __launch_bounds__(256) void pool_kernel(const float* __restrict__ x,
                                                   float* __restrict__ pooled) {
    int w = blockIdx.x * 4 + (threadIdx.x >> 6);
    int lane = threadIdx.x & 63;
    const float* p = x + (size_t)w * HW_;
    float s = 0.f;
    for (int i = lane; i < HW_; i += 64) s += p[i];
    for (int off = 32; off; off >>= 1) s += __shfl_down(s, off);
    if (lane == 0) pooled[w] = s * (1.0f / HW_);
}

// ---------------- Kernel 2: SE MLP + softmax (reads partial pools) ----------------
__global__ __launch_bounds__(256) void se3_kernel(const float* __restrict__ partial,
                                                  const float* __restrict__ fc1_w,
                                                  const float* __restrict__ fc2_w,
                                                  const float* __restrict__ fc2_b,
                                                  float* __restrict__ prob) {
    __shared__ float pl[CIN_];
    __shared__ float h[HID_];
    __shared__ float wb[16640];
    int b = blockIdx.x, t = threadIdx.x;
    {
        float s = 0.f;
        for (int pt = 0; pt < 25; ++pt)
            s += partial[((size_t)b * 25 + pt) * CIN_ + t];
        pl[t] = s;
    }
    #pragma unroll
    for (int i = 0; i < 16; ++i) {
        int l = t + i * 256;
        float4 v = *(const float4*)(fc1_w + (size_t)l * 4);
        int r = l >> 6, cc = (l & 63) * 4;
        float* dst = &wb[r * 257 + cc];
        dst[0] = v.x; dst[1] = v.y; dst[2] = v.z; dst[3] = v.w;
    }
    __syncthreads();
    if (t < HID_) {
        float s = 0.f;
        const float* wr = &wb[t * 257];
        for (int c = 0; c < CIN_; ++c) s += pl[c] * wr[c];
        h[t] = fmaxf(s, 0.f);
    }
    float yk[KEXP_];
    for (int k = 0; k < KEXP_; ++k) {
        __syncthreads();
        #pragma unroll
        for (int i = 0; i < 16; ++i) {
            int l = t + i * 256;
            float4 v = *(const float4*)(fc2_w + (size_t)k * COUT_ * HID_ + (size_t)l * 4);
            int o = l >> 4, jj = (l & 15) * 4;
            float* dst = &wb[o * 65 + jj];
            dst[0] = v.x; dst[1] = v.y; dst[2] = v.z; dst[3] = v.w;
        }
        __syncthreads();
        float s = fc2_b[k * COUT_ + t];
        const float* wr = &wb[t * 65];
        #pragma unroll
        for (int j = 0; j < HID_; ++j) s += h[j] * wr[j];
        yk[k] = s * 0.125f;
    }
    float m = yk[0];
    for (int k = 1; k < KEXP_; ++k) m = fmaxf(m, yk[k]);
    float e[KEXP_], sum = 0.f;
    for (int k = 0; k < KEXP_; ++k) { e[k] = expf(yk[k] - m); sum += e[k]; }
    float inv = 1.0f / sum;
    for (int k = 0; k < KEXP_; ++k)
        prob[b * (KEXP_ * COUT_) + k * COUT_ + t] = e[k] * inv;
}

// ---------------- SE from pooled (fallback path only) ----------------
__global__ __launch_bounds__(256) void se2_kernel(const float* __restrict__ pooled,
                                                  const float* __restrict__ fc1_w,
                                                  const float* __restrict__ fc2_w,
                                                  const float* __restrict__ fc2_b,
                                                  float* __restrict__ prob) {
    __shared__ float pl[CIN_];
    __shared__ float h[HID_];
    __shared__ float wb[16640];
    int b = blockIdx.x, t = threadIdx.x;
    pl[t] = pooled[b * CIN_ + t];
    #pragma unroll
    for (int i = 0; i < 16; ++i) {
        int l = t + i * 256;
        float4 v = *(const float4*)(fc1_w + (size_t)l * 4);
        int r = l >> 6, cc = (l & 63) * 4;
        float* dst = &wb[r * 257 + cc];
        dst[0] = v.x; dst[1] = v.y; dst[2] = v.z; dst[3] = v.w;
    }
    __syncthreads();
    if (t < HID_) {
        float s = 0.f;
        const float* wr = &wb[t * 257];
        for (int c = 0; c < CIN_; ++c) s += pl[c] * wr[c];
        h[t] = fmaxf(s, 0.f);
    }
    float yk[KEXP_];
    for (int k = 0; k < KEXP_; ++k) {
        __syncthreads();
        #pragma unroll
        for (int i = 0; i < 16; ++i) {
            int l = t + i * 256;
            float4 v = *(const float4*)(fc2_w + (size_t)k * COUT_ * HID_ + (size_t)l * 4);
            int o = l >> 4, jj = (l & 15) * 4;
            float* dst = &wb[o * 65 + jj];
            dst[0] = v.x; dst[1] = v.y; dst[2] = v.z; dst[3] = v.w;
        }
        __syncthreads();
        float s = fc2_b[k * COUT_ + t];
        const float* wr = &wb[t * 65];
        #pragma unroll
        for (int j = 0; j < HID_; ++j) s += h[j] * wr[j];
        yk[k] = s * 0.125f;
    }
    float m = yk[0];
    for (int k = 1; k < KEXP_; ++k) m = fmaxf(m, yk[k]);
    float e[KEXP_], sum = 0.f;
    for (int k = 0; k < KEXP_; ++k) { e[k] = expf(yk[k] - m); sum += e[k]; }
    float inv = 1.0f / sum;
    for (int k = 0; k < KEXP_; ++k)
        prob[b * (KEXP_ * COUT_) + k * COUT_ + t] = e[k] * inv;
}

// ---------------- Kernel 3: aggregate expert weights -> MFMA-fragment layout ----------------
// agg element (b, oc, ic, rs) at:
//   (b*16 + icc*4 + kk)*36864 + rs*4096 + og*512 + (kh*32+ml)*8 + j      [bf16 elems]
// where icc=ic>>6, kk=(ic>>4)&3, kh=(ic>>3)&1, j=ic&7, og=oc>>5, ml=oc&31.
// A wave-load of one fragment (fixed b,icc,kk,rs,og) is 64 lanes x 16B contiguous = 1KB.
// grid = 256: og = gid&7, icc = (gid>>3)&3, kk = (gid>>5)&3, bh = gid>>7 (16 b's each)
__global__ __launch_bounds__(256) void agg4_kernel(const float* __restrict__ weight,
                                                   const float* __restrict__ prob,
                                                   unsigned short* __restrict__ agg) {
    __shared__ float wlds[4][32][145];   // [k][oc-ml][(kh*8+j)*9+rs], pad 144->145 (odd stride)
    int gid = blockIdx.x;
    int og  = gid & 7;
    int icc = (gid >> 3) & 3;
    int kk  = (gid >> 5) & 3;
    int bh  = gid >> 7;
    int oc0 = og * 32;
    int ic0 = icc * 64 + kk * 16;
    int t = threadIdx.x;

    // stage weight[k][oc0..oc0+31][ic0..ic0+15][rs 0..8] -> LDS (each element read once globally)
    #pragma unroll
    for (int i = 0; i < 18; ++i) {
        int idx = t + i * 256;             // 0..4607 float4s
        int k  = idx / 1152;
        int r  = idx - k * 1152;
        int oc = r / 36;
        int f4 = r - oc * 36;
        float4 v = *(const float4*)(weight + ((size_t)(k * COUT_ + oc0 + oc) * CIN_ + ic0) * 9 + f4 * 4);
        float* dst = &wlds[k][oc][f4 * 4];
        dst[0] = v.x; dst[1] = v.y; dst[2] = v.z; dst[3] = v.w;
    }

    int lane = t & 63, wv = t >> 6;
    int ml = lane & 31, kh = lane >> 5;

    // preload probabilities for this wave's 4 batches
    float pbr[4][4];
    #pragma unroll
    for (int bi = 0; bi < 4; ++bi) {
        int b = bh * 16 + wv * 4 + bi;
        #pragma unroll
        for (int k = 0; k < 4; ++k)
            pbr[bi][k] = prob[(size_t)b * (KEXP_ * COUT_) + k * COUT_ + oc0 + ml];
    }
    __syncthreads();

    for (int rs = 0; rs < 9; ++rs) {
        float wreg[4][8];
        #pragma unroll
        for (int k = 0; k < 4; ++k)
            #pragma unroll
            for (int j = 0; j < 8; ++j)
                wreg[k][j] = wlds[k][ml][(kh * 8 + j) * 9 + rs];
        #pragma unroll
        for (int bi = 0; bi < 4; ++bi) {
            int b = bh * 16 + wv * 4 + bi;
            ushort8v pack;
            #pragma unroll
            for (int j = 0; j < 8; ++j) {
                float s = pbr[bi][0] * wreg[0][j] + pbr[bi][1] * wreg[1][j]
                        + pbr[bi][2] * wreg[2][j] + pbr[bi][3] * wreg[3][j];
                pack[j] = f2bf(s);
            }
            *(ushort8v*)(agg + (size_t)(b * 16 + icc * 4 + kk) * 36864
                             + (size_t)rs * 4096 + og * 512 + lane * 8) = pack;
        }
    }
}

// ---------------- Kernel 4: MFMA implicit-GEMM conv, 4-row strips for occupancy ----------------
// grid = 448: b = gid&31, half = (gid>>5)&1, rowblk = gid>>6 (0..6, 4 rows each)
// Same-b blocks share gid mod 8 -> same XCD -> agg slice is L2-local.
__global__ __launch_bounds__(256, 2) void conv_mfma5_kernel(const unsigned short* __restrict__ x_t,
                                                            const unsigned short* __restrict__ agg,
                                                            float* __restrict__ out) {
    __shared__ __align__(16) short Xs[2][6 * 35 * 72];   // 2 x 30240 B = 60480 B -> 2 blocks/CU

    int gid = blockIdx.x;
    int b      = gid & 31;
    int half   = (gid >> 5) & 1;
    int oc0    = half * 128;
    int rowblk = gid >> 6;
    int py0 = rowblk * 4;

    int t = threadIdx.x;
    int lane = t & 63, w = t >> 6;
    int ml = lane & 31, kh = lane >> 5;
    int og = half * 4 + w;

    floatx16 acc[4];
    #pragma unroll
    for (int j = 0; j < 4; ++j)
        #pragma unroll
        for (int r = 0; r < 16; ++r) acc[j][r] = 0.f;

    const unsigned short* xtb = x_t + (size_t)b * HW_ * CIN_;
    // fragment base: agg + b*589824 + og*512 + lane*8 ; strides (bf16 elems):
    //   icc: 147456, kk: 36864, rs: 4096 (tap ky stride = 3*4096 = 12288)
    const unsigned short* aln = agg + (size_t)b * 589824 + og * 512 + lane * 8;

    // ---- stage chunk 0 into buf 0 (6 rows x 35 cols x 64 ic = 1680 short8s) ----
    {
        #pragma unroll
        for (int i = 0; i < 7; ++i) {
            int l = t + i * 256;
            if (l < 1680) {
                int pos = l >> 3, g = l & 7;
                int row = pos / 35, col = pos - row * 35;
                int gy = py0 - 1 + row, gx = col - 1;
                short8 v = (short8)0;
                if ((unsigned)gy < 28u && (unsigned)gx < 28u)
                    v = *(const short8*)(xtb + ((size_t)(gy * W_ + gx)) * CIN_ + g * 8);
                *(short8*)&Xs[0][pos * 72 + g * 8] = v;
            }
        }
    }

    // ---- prologue: A fragments for (icc=0, kk=0, dx=0), taps ky=0,1,2 ----
    short8 Acur0, Acur1, Acur2, Anext0, Anext1, Anext2;
    Acur0 = *(const short8*)(aln);
    Acur1 = *(const short8*)(aln + 12288);
    Acur2 = *(const short8*)(aln + 24576);
    // rolling "next pair" state
    int dxn = 1, kkn = 0, icn = 0;

    __syncthreads();

    for (int c = 0; c < 4; ++c) {
        int ic0 = c * 64;
        const short* xb = &Xs[c & 1][0];

        // issue staging loads for next chunk (held in regs, written after compute)
        short8 Xl[7];
        if (c < 3) {
            #pragma unroll
            for (int i = 0; i < 7; ++i) {
                int l = t + i * 256;
                short8 v = (short8)0;
                if (l < 1680) {
                    int pos = l >> 3, g = l & 7;
                    int row = pos / 35, col = pos - row * 35;
                    int gy = py0 - 1 + row, gx = col - 1;
                    if ((unsigned)gy < 28u && (unsigned)gx < 28u)
                        v = *(const short8*)(xtb + ((size_t)(gy * W_ + gx)) * CIN_ + ic0 + 64 + g * 8);
                }
                Xl[i] = v;
            }
        }

        for (int kk = 0; kk < 4; ++kk) {
            for (int dx = 0; dx < 3; ++dx) {
                // prefetch A fragments for next (icc,kk,dx) — 3 coalesced 1KB wave loads
                if (icn < 256) {
                    const unsigned short* ap = aln + (size_t)(icn >> 6) * 147456
                                                   + (size_t)kkn * 36864 + (size_t)dxn * 4096;
                    Anext0 = *(const short8*)(ap);
                    Anext1 = *(const short8*)(ap + 12288);
                    Anext2 = *(const short8*)(ap + 24576);
                    ++dxn;
                    if (dxn == 3) { dxn = 0; ++kkn; if (kkn == 4) { kkn = 0; icn += 64; } }
                }
                // compute: 6 Xs rows, B reused across 3 dy taps (4 out rows)
                int va = (ml + dx) * 72 + kk * 16 + kh * 8;
                #pragma unroll
                for (int r = 0; r < 6; ++r) {
                    short8 Bf = *(const short8*)&xb[r * 2520 + va];
                    if (r <= 3)
                        acc[r]     = __builtin_amdgcn_mfma_f32_32x32x16_bf16(Acur0, Bf, acc[r], 0, 0, 0);
                    if (r >= 1 && r - 1 <= 3)
                        acc[r - 1] = __builtin_amdgcn_mfma_f32_32x32x16_bf16(Acur1, Bf, acc[r - 1], 0, 0, 0);
                    if (r >= 2)
                        acc[r - 2] = __builtin_amdgcn_mfma_f32_32x32x16_bf16(Acur2, Bf, acc[r - 2], 0, 0, 0);
                }
                Acur0 = Anext0; Acur1 = Anext1; Acur2 = Anext2;
            }
        }

        if (c < 3) {
            short* dstb = &Xs[(c & 1) ^ 1][0];
            #pragma unroll
            for (int i = 0; i < 7; ++i) {
                int l = t + i * 256;
                if (l < 1680) {
                    int pos = l >> 3, g = l & 7;
                    *(short8*)&dstb[pos * 72 + g * 8] = Xl[i];
                }
            }
        }
        __syncthreads();
    }

    // ---- epilogue: D layout col=lane&31, row=(reg&3)+8*(reg>>2)+4*(lane>>5) ----
    if (ml < W_) {
        #pragma unroll
        for (int j = 0; j < 4; ++j) {
            float* op = out + ((size_t)(b * COUT_ + oc0 + w * 32)) * HW_ + (py0 + j) * W_ + ml;
            #pragma unroll
            for (int r = 0; r < 16; ++r) {
                int ocd = (r & 3) + 8 * (r >> 2) + 4 * kh;
                op[(size_t)ocd * HW_] = acc[j][r];
            }
        }
    }
}

// ---------------- Fallback fp32 direct conv ----------------
__global__ __launch_bounds__(256) void conv_kernel(const float* __restrict__ x,
                                                   const float* __restrict__ weight,
                                                   const float* __restrict__ prob,
                                                   float* __restrict__ out) {
    __shared__ float xs[30 * 30];
    __shared__ float wagg[8][32][12];
    __shared__ float pl[KEXP_][8];

    int b  = blockIdx.x >> 5;
    int o0 = (blockIdx.x & 31) * 8;
    int t  = threadIdx.x;

    if (t < 32) {
        int k = t >> 3, oc = t & 7;
        pl[k][oc] = prob[b * (KEXP_ * COUT_) + k * COUT_ + o0 + oc];
    }
    int p0 = t;
    int pr[4], pc[4];
    bool pv[4];
    #pragma unroll
    for (int j = 0; j < 4; ++j) {
        int p = p0 + j * 256;
        pv[j] = p < HW_;
        pr[j] = p / W_;
        pc[j] = p % W_;
    }
    float acc[8][4];
    #pragma unroll
    for (int oc = 0; oc < 8; ++oc)
        #pragma unroll
        for (int j = 0; j < 4; ++j) acc[oc][j] = 0.f;

    int aoc = t >> 5, aii = t & 31;

    for (int ic0 = 0; ic0 < CIN_; ic0 += 32) {
        __syncthreads();
        {
            float w9[9];
            #pragma unroll
            for (int j = 0; j < 9; ++j) w9[j] = 0.f;
            int i = ic0 + aii;
            #pragma unroll
            for (int k = 0; k < KEXP_; ++k) {
                float pk = pl[k][aoc];
                const float* wp = weight + ((size_t)(k * COUT_ + o0 + aoc) * CIN_ + i) * 9;
                #pragma unroll
                for (int j = 0; j < 9; ++j) w9[j] += pk * wp[j];
            }
            #pragma unroll
            for (int j = 0; j < 9; ++j) wagg[aoc][aii][j] = w9[j];
        }
        for (int ii = 0; ii < 32; ++ii) {
            int i = ic0 + ii;
            __syncthreads();
            const float* xp = x + (size_t)(b * CIN_ + i) * HW_;
            for (int e = t; e < 900; e += 256) {
                int ry = e / 30, cx = e - ry * 30;
                int gy = ry - 1, gx = cx - 1;
                float v = 0.f;
                if ((unsigned)gy < 28u && (unsigned)gx < 28u) v = xp[gy * W_ + gx];
                xs[e] = v;
            }
            __syncthreads();
            float xv[4][9];
            #pragma unroll
            for (int j = 0; j < 4; ++j) {
                if (pv[j]) {
                    const float* xr = &xs[pr[j] * 30 + pc[j]];
                    xv[j][0] = xr[0];  xv[j][1] = xr[1];  xv[j][2] = xr[2];
                    xv[j][3] = xr[30]; xv[j][4] = xr[31]; xv[j][5] = xr[32];
                    xv[j][6] = xr[60]; xv[j][7] = xr[61]; xv[j][8] = xr[62];
                } else {
                    #pragma unroll
                    for (int q = 0; q < 9; ++q) xv[j][q] = 0.f;
                }
            }
            #pragma unroll
            for (int oc = 0; oc < 8; ++oc) {
                float4 wa = *(const float4*)&wagg[oc][ii][0];
                float4 wb2 = *(const float4*)&wagg[oc][ii][4];
                float  wc = wagg[oc][ii][8];
                #pragma unroll
                for (int j = 0; j < 4; ++j) {
                    acc[oc][j] += xv[j][0] * wa.x + xv[j][1] * wa.y + xv[j][2] * wa.z
                                + xv[j][3] * wa.w + xv[j][4] * wb2.x + xv[j][5] * wb2.y
                                + xv[j][6] * wb2.z + xv[j][7] * wb2.w + xv[j][8] * wc;
                }
            }
        }
    }
    #pragma unroll
    for (int oc = 0; oc < 8; ++oc) {
        float* op = out + (size_t)(b * COUT_ + o0 + oc) * HW_ + p0;
        #pragma unroll
        for (int j = 0; j < 4; ++j)
            if (pv[j]) op[j * 256] = acc[oc][j];
    }
}

extern "C" void kernel_launch(void* const* d_in, const int* in_sizes, int n_in,
                              void* d_out, int out_size, void* d_ws, size_t ws_size,
                              hipStream_t stream) {
    const float* x     = (const float*)d_in[0];
    const float* fc1_w = (const float*)d_in[1];
    const float* fc2_w = (const float*)d_in[2];
    const float* fc2_b = (const float*)d_in[3];
    const float* weight= (const float*)d_in[4];
    float* out = (float*)d_out;

    char* ws = (char*)d_ws;
    // layout (main path): prob @0 (128KB), x_t @131072 (12.85MB), agg @12976128 (37.75MB)
    // partial pools overlap the agg region (consumed by se3 before agg4 writes)
    float* prob = (float*)(ws);
    unsigned short* x_t = (unsigned short*)(ws + 131072);
    unsigned short* agg = (unsigned short*)(ws + 12976128);
    float* partial = (float*)(ws + 12976128);          // 32*25*256 floats = 819200 B
    const size_t WS_NEED = 12976128 + (size_t)B_ * 9 * COUT_ * CIN_ * 2;  // 50724864

    if (ws_size >= WS_NEED) {
        xpose_pool_kernel<<<B_ * 8 * 25, 256, 0, stream>>>(x, x_t, partial);
        se3_kernel<<<B_, 256, 0, stream>>>(partial, fc1_w, fc2_w, fc2_b, prob);
        agg4_kernel<<<256, 256, 0, stream>>>(weight, prob, agg);
        conv_mfma5_kernel<<<448, 256, 0, stream>>>(x_t, agg, out);
    } else {
        float* pooled = (float*)(ws + 131072);
        pool_kernel<<<(B_ * CIN_) / 4, 256, 0, stream>>>(x, pooled);
        se2_kernel<<<B_, 256, 0, stream>>>(pooled, fc1_w, fc2_w, fc2_b, prob);
        conv_kernel<<<B_ * (COUT_ / 8), 256, 0, stream>>>(x, weight, prob, out);
    }
}